// Round 1
// baseline (24274.857 us; speedup 1.0000x reference)
//
#include <hip/hip_runtime.h>
#include <hip/hip_cooperative_groups.h>

namespace cg = cooperative_groups;

#define NN 2048   // reservoir size
#define NB 32     // batch
#define NT 500    // time steps
#define WGS 512   // threads per workgroup
#define NWG 256   // workgroups

// Tiling:
//  - WG owns 16 neurons (i) x 16 batches (b); 128 i-tiles x 2 b-tiles = 256 WGs.
//  - Thread t: jh = t>>6 (8-way j split, 256 j each), r = t&63,
//              iL = r>>2 (16 neurons), bq = r&3 (4 batch-quads of 4).
//  - Each thread accumulates dot for (i, b0+bq*4 .. +3) over its j-range.
//  - 8 partials per output reduced in LDS; threads t<64 own the state
//    (mem, prev-spike) for 4 batches of one neuron in registers.
//  - Spikes live transposed spkT[j][b] (float 0/1), double-buffered in ws.

__launch_bounds__(WGS, 2)
__global__ void reservoir_kernel(const float* __restrict__ x,
                                 const float* __restrict__ W,
                                 const float* __restrict__ bias,
                                 float* __restrict__ out,
                                 float* __restrict__ ws)
{
    cg::grid_group grid = cg::this_grid();

    __shared__ float4 lds_part[8 * 64];  // [jh][r] partial dots (float4 = 4 batches)
    __shared__ float  lds_s[256];        // staged spikes for coalesced output
    __shared__ float  lds_m[256];        // staged mems
    __shared__ int    lds_cnt[64];

    float* spkT0 = ws;                      // [2048][32]
    float* spkT1 = ws + (size_t)NN * NB;    // [2048][32]
    int*   wgpart = (int*)(ws + 2 * (size_t)NN * NB);  // [256]

    const int wg = blockIdx.x;
    const int t  = threadIdx.x;
    const int i0 = (wg & 127) * 16;
    const int b0 = (wg >> 7) * 16;
    const int jh = t >> 6;          // 0..7
    const int r  = t & 63;
    const int iL = r >> 2;          // 0..15
    const int bq = r & 3;           // 0..3
    const int i  = i0 + iL;

    // zero the step-0 spike buffer (read before first write)
    {
        int g = wg * WGS + t;
        if (g < NN * NB) spkT0[g] = 0.0f;
    }

    // register state for updater threads (t < 64): 4 batches of neuron i
    float mem0 = 0.f, mem1 = 0.f, mem2 = 0.f, mem3 = 0.f;
    float sp0 = 0.f, sp1 = 0.f, sp2 = 0.f, sp3 = 0.f;
    int   cnt = 0;
    float biasv = 0.f;
    if (t < 64) biasv = bias[i];

    const float4* wrow = (const float4*)(W + (size_t)i * NN + jh * 256);

    float* spk_rec = out + 1;
    float* mem_rec = out + 1 + (size_t)NT * NB * NN;

    grid.sync();

    for (int step = 0; step < NT; ++step) {
        const float* spkR = (step & 1) ? spkT1 : spkT0;   // read spikes from step-1
        float*       spkW = (step & 1) ? spkT0 : spkT1;   // publish spikes for step+1

        const float4* srow = (const float4*)(spkR + (size_t)jh * 256 * NB + b0 + bq * 4);
        float a0 = 0.f, a1 = 0.f, a2 = 0.f, a3 = 0.f;
        #pragma unroll 4
        for (int jj = 0; jj < 64; ++jj) {
            float4 w = wrow[jj];
            const float4* sp = srow + (size_t)jj * 32;  // 4 j's * 8 float4/row
            float4 s0 = sp[0];
            float4 s1 = sp[8];
            float4 s2 = sp[16];
            float4 s3 = sp[24];
            a0 += w.x * s0.x; a1 += w.x * s0.y; a2 += w.x * s0.z; a3 += w.x * s0.w;
            a0 += w.y * s1.x; a1 += w.y * s1.y; a2 += w.y * s1.z; a3 += w.y * s1.w;
            a0 += w.z * s2.x; a1 += w.z * s2.y; a2 += w.z * s2.z; a3 += w.z * s2.w;
            a0 += w.w * s3.x; a1 += w.w * s3.y; a2 += w.w * s3.z; a3 += w.w * s3.w;
        }
        lds_part[jh * 64 + r] = make_float4(a0, a1, a2, a3);
        __syncthreads();

        if (t < 64) {
            float4 d = lds_part[t];  // jh = 0 partial
            #pragma unroll
            for (int k = 1; k < 8; ++k) {
                float4 p = lds_part[k * 64 + t];
                d.x += p.x; d.y += p.y; d.z += p.z; d.w += p.w;
            }
            const int bb = b0 + bq * 4;
            float xv0 = x[(size_t)(bb + 0) * NT + step];
            float xv1 = x[(size_t)(bb + 1) * NT + step];
            float xv2 = x[(size_t)(bb + 2) * NT + step];
            float xv3 = x[(size_t)(bb + 3) * NT + step];

            float base0 = 0.95f * mem0 + xv0 + d.x + biasv;
            float base1 = 0.95f * mem1 + xv1 + d.y + biasv;
            float base2 = 0.95f * mem2 + xv2 + d.z + biasv;
            float base3 = 0.95f * mem3 + xv3 + d.w + biasv;

            float nm0 = base0 * (1.0f - sp0);
            float nm1 = base1 * (1.0f - sp1);
            float nm2 = base2 * (1.0f - sp2);
            float nm3 = base3 * (1.0f - sp3);

            float ns0 = (nm0 > 1.0f) ? 1.0f : 0.0f;
            float ns1 = (nm1 > 1.0f) ? 1.0f : 0.0f;
            float ns2 = (nm2 > 1.0f) ? 1.0f : 0.0f;
            float ns3 = (nm3 > 1.0f) ? 1.0f : 0.0f;

            mem0 = nm0; mem1 = nm1; mem2 = nm2; mem3 = nm3;
            sp0 = ns0; sp1 = ns1; sp2 = ns2; sp3 = ns3;
            cnt += (int)ns0 + (int)ns1 + (int)ns2 + (int)ns3;

            // publish spikes for next step (transposed layout [j=i][b])
            *(float4*)(spkW + (size_t)i * NB + bb) = make_float4(ns0, ns1, ns2, ns3);

            // stage for coalesced global writes: lds[(b_local)*16 + i_local]
            lds_m[(bq * 4 + 0) * 16 + iL] = nm0; lds_s[(bq * 4 + 0) * 16 + iL] = ns0;
            lds_m[(bq * 4 + 1) * 16 + iL] = nm1; lds_s[(bq * 4 + 1) * 16 + iL] = ns1;
            lds_m[(bq * 4 + 2) * 16 + iL] = nm2; lds_s[(bq * 4 + 2) * 16 + iL] = ns2;
            lds_m[(bq * 4 + 3) * 16 + iL] = nm3; lds_s[(bq * 4 + 3) * 16 + iL] = ns3;
        }
        __syncthreads();

        if (t < 256) {
            int bl = t >> 4, il = t & 15;
            size_t o = ((size_t)step * NB + (b0 + bl)) * (size_t)NN + i0 + il;
            spk_rec[o] = lds_s[t];
            mem_rec[o] = lds_m[t];
        }
        grid.sync();
    }

    // average firing rate
    if (t < 64) lds_cnt[t] = cnt;
    __syncthreads();
    if (t == 0) {
        int s = 0;
        #pragma unroll
        for (int k = 0; k < 64; ++k) s += lds_cnt[k];
        wgpart[wg] = s;
    }
    grid.sync();
    if (wg == 0 && t == 0) {
        long long s = 0;
        for (int k = 0; k < NWG; ++k) s += wgpart[k];
        out[0] = (float)((double)s / (double)((long long)NT * NB * NN));
    }
}

extern "C" void kernel_launch(void* const* d_in, const int* in_sizes, int n_in,
                              void* d_out, int out_size, void* d_ws, size_t ws_size,
                              hipStream_t stream) {
    const float* x    = (const float*)d_in[0];  // (32, 500, 1)
    const float* W    = (const float*)d_in[1];  // (2048, 2048)
    const float* bias = (const float*)d_in[2];  // (2048,)
    float* out = (float*)d_out;
    float* ws  = (float*)d_ws;

    void* args[] = { (void*)&x, (void*)&W, (void*)&bias, (void*)&out, (void*)&ws };
    hipLaunchCooperativeKernel((const void*)reservoir_kernel,
                               dim3(NWG), dim3(WGS), args, 0, stream);
}

// Round 3
// 22714.421 us; speedup vs baseline: 1.0687x; 1.0687x over previous
//
#include <hip/hip_runtime.h>
#include <hip/hip_cooperative_groups.h>

namespace cg = cooperative_groups;

#define NN 2048
#define NB 32
#define NT 500
#define WGS 512
#define NWG 256

// WG wg owns rows i0 = wg*8 .. i0+7, ALL 32 batches.
// Compute thread t: rh = t>>8 (row half, 4 rows), jh = (t>>5)&7 (j-chunk of 256),
//                   b = t&31 (batch). 4 rows share each bit expansion.
// Numeric order per (i,b) dot == R1 (passing kernel), bit-for-bit:
//   8 chunk partials, each a sequential fma over j, j+1, j+2, j+3 per float4,
//   combined d = ((c0+c1)+c2)...+c7 by one combine thread.
// Spikes bit-packed: uint32 per j (32 batches), double-buffered in ws,
// staged to LDS (8 KB) once per WG per step.

__launch_bounds__(WGS, 2)
__global__ void reservoir_kernel(const float* __restrict__ x,
                                 const float* __restrict__ W,
                                 const float* __restrict__ bias,
                                 float* __restrict__ out,
                                 float* __restrict__ ws)
{
    cg::grid_group grid = cg::this_grid();

    __shared__ unsigned int lbits[NN];      // 8 KB spike bits (all 32 batches)
    __shared__ float lpart[8][8][32];       // 8 KB [jh][i_local][b]
    __shared__ float lout[2][NB][9];        // padded (bank-conflict) output stage
    __shared__ int   lcnt[8];

    unsigned int* bitsG = (unsigned int*)ws;                 // [2][2048]
    int* wgpart = (int*)((char*)ws + 2 * NN * sizeof(unsigned int));  // [NWG]

    const int wg = blockIdx.x;
    const int t  = threadIdx.x;
    const int i0 = wg * 8;

    // zero both spike-bit buffers (deterministic per launch)
    { int g = wg * WGS + t; if (g < 2 * NN) bitsG[g] = 0u; }

    // compute-thread identity
    const int rh4 = (t >> 8) * 4;      // 0 or 4
    const int jh  = (t >> 5) & 7;      // chunk 0..7
    const int b   = t & 31;            // batch 0..31

    const float4* wr0 = (const float4*)(W + (size_t)(i0 + rh4 + 0) * NN) + jh * 64;
    const float4* wr1 = (const float4*)(W + (size_t)(i0 + rh4 + 1) * NN) + jh * 64;
    const float4* wr2 = (const float4*)(W + (size_t)(i0 + rh4 + 2) * NN) + jh * 64;
    const float4* wr3 = (const float4*)(W + (size_t)(i0 + rh4 + 3) * NN) + jh * 64;

    // combine-thread identity (t < 256): (row cil, batch cb)
    const int cil = t >> 5;            // valid for t<256: 0..7
    const int cb  = t & 31;
    float mem = 0.0f, sp = 0.0f;
    float biasv = 0.0f;
    const float* xb = x;
    if (t < 256) { biasv = bias[i0 + cil]; xb = x + (size_t)cb * NT; }
    int cnt = 0;

    float* spk_rec = out + 1;
    float* mem_rec = out + 1 + (size_t)NT * NB * NN;

    grid.sync();

    for (int step = 0; step < NT; ++step) {
        const int cur = step & 1;

        // stage spike bits (8 KB) to LDS, coalesced
        ((uint4*)lbits)[t] = ((const uint4*)(bitsG + (size_t)cur * NN))[t];
        __syncthreads();

        // chunk partials: 4 rows x 1 batch over 256 consecutive j (sequential order)
        float c0 = 0.0f, c1 = 0.0f, c2 = 0.0f, c3 = 0.0f;
        const uint4* bp = ((const uint4*)lbits) + jh * 64;
        #pragma unroll 2
        for (int jj = 0; jj < 64; ++jj) {
            const float4 w0 = wr0[jj];
            const float4 w1 = wr1[jj];
            const float4 w2 = wr2[jj];
            const float4 w3 = wr3[jj];
            const uint4  bu = bp[jj];
            float s;
            s = (float)((bu.x >> b) & 1u);
            c0 = fmaf(w0.x, s, c0); c1 = fmaf(w1.x, s, c1);
            c2 = fmaf(w2.x, s, c2); c3 = fmaf(w3.x, s, c3);
            s = (float)((bu.y >> b) & 1u);
            c0 = fmaf(w0.y, s, c0); c1 = fmaf(w1.y, s, c1);
            c2 = fmaf(w2.y, s, c2); c3 = fmaf(w3.y, s, c3);
            s = (float)((bu.z >> b) & 1u);
            c0 = fmaf(w0.z, s, c0); c1 = fmaf(w1.z, s, c1);
            c2 = fmaf(w2.z, s, c2); c3 = fmaf(w3.z, s, c3);
            s = (float)((bu.w >> b) & 1u);
            c0 = fmaf(w0.w, s, c0); c1 = fmaf(w1.w, s, c1);
            c2 = fmaf(w2.w, s, c2); c3 = fmaf(w3.w, s, c3);
        }
        lpart[jh][rh4 + 0][b] = c0;
        lpart[jh][rh4 + 1][b] = c1;
        lpart[jh][rh4 + 2][b] = c2;
        lpart[jh][rh4 + 3][b] = c3;
        __syncthreads();

        if (t < 256) {
            // sequential combine over chunks (== R1 order)
            float d = lpart[0][cil][cb];
            #pragma unroll
            for (int k = 1; k < 8; ++k) d += lpart[k][cil][cb];

            float xv   = xb[step];
            float base = 0.95f * mem + xv + d + biasv;
            float nm   = base * (1.0f - sp);
            float ns   = (nm > 1.0f) ? 1.0f : 0.0f;
            mem = nm; sp = ns;
            cnt += (int)ns;

            // publish spike bits for next step: wave w2 covers rows 2w2, 2w2+1
            unsigned long long bal = __ballot(ns > 0.5f);
            unsigned int* bw = bitsG + (size_t)(1 - cur) * NN;
            const int l  = t & 63;
            const int w2 = t >> 6;
            if (l == 0)  bw[i0 + 2 * w2]     = (unsigned int)(bal & 0xFFFFFFFFull);
            if (l == 32) bw[i0 + 2 * w2 + 1] = (unsigned int)(bal >> 32);

            lout[0][cb][cil] = ns;
            lout[1][cb][cil] = nm;
        }
        __syncthreads();

        // coalesced-ish output stores (8 consecutive floats per (step,b))
        {
            const int arr = t >> 8;
            const int r2  = t & 255;
            const int bb  = r2 >> 3;
            const int il  = r2 & 7;
            size_t o = ((size_t)step * NB + bb) * (size_t)NN + i0 + il;
            if (arr == 0) __builtin_nontemporal_store(lout[0][bb][il], &spk_rec[o]);
            else          __builtin_nontemporal_store(lout[1][bb][il], &mem_rec[o]);
        }
        grid.sync();
    }

    // average firing rate
    #pragma unroll
    for (int d2 = 1; d2 < 64; d2 <<= 1) cnt += __shfl_xor(cnt, d2, 64);
    if ((t & 63) == 0) lcnt[t >> 6] = cnt;
    __syncthreads();
    if (t == 0) {
        int s = 0;
        #pragma unroll
        for (int k = 0; k < 8; ++k) s += lcnt[k];
        wgpart[wg] = s;
    }
    grid.sync();
    if (wg == 0) {
        int ps = (t < NWG) ? wgpart[t] : 0;
        #pragma unroll
        for (int d2 = 1; d2 < 64; d2 <<= 1) ps += __shfl_xor(ps, d2, 64);
        if ((t & 63) == 0) lcnt[t >> 6] = ps;
        __syncthreads();
        if (t == 0) {
            long long s2 = 0;
            #pragma unroll
            for (int k = 0; k < 8; ++k) s2 += lcnt[k];
            out[0] = (float)((double)s2 / (double)((long long)NT * NB * NN));
        }
    }
}

extern "C" void kernel_launch(void* const* d_in, const int* in_sizes, int n_in,
                              void* d_out, int out_size, void* d_ws, size_t ws_size,
                              hipStream_t stream) {
    const float* x    = (const float*)d_in[0];  // (32, 500, 1)
    const float* W    = (const float*)d_in[1];  // (2048, 2048)
    const float* bias = (const float*)d_in[2];  // (2048,)
    float* out = (float*)d_out;
    float* ws  = (float*)d_ws;

    void* args[] = { (void*)&x, (void*)&W, (void*)&bias, (void*)&out, (void*)&ws };
    hipLaunchCooperativeKernel((const void*)reservoir_kernel,
                               dim3(NWG), dim3(WGS), args, 0, stream);
}